// Round 7
// baseline (642.762 us; speedup 1.0000x reference)
//
#include <hip/hip_runtime.h>
#include <hip/hip_bf16.h>

typedef __attribute__((ext_vector_type(8))) short short8_t;
typedef __attribute__((ext_vector_type(8))) __bf16 bf16x8;
typedef __attribute__((ext_vector_type(4))) float f32x4;

__device__ __forceinline__ void gload16(const void* g, void* l) {
  __builtin_amdgcn_global_load_lds(
      (const __attribute__((address_space(1))) void*)g,
      (__attribute__((address_space(3))) void*)l, 16, 0, 0);
}

__device__ __forceinline__ unsigned short f2bf(float f) {
  __hip_bfloat16 h = __float2bfloat16(f);
  return __builtin_bit_cast(unsigned short, h);
}

#define BARRIER() asm volatile("s_barrier" ::: "memory")

// ---------------- conversion kernels ----------------

__global__ void k_cvt_feat(const float* __restrict__ in, unsigned short* __restrict__ out) {
  const size_t N = (size_t)4096 * 8192;
  size_t i = ((size_t)blockIdx.x * 256 + threadIdx.x) * 4;
  const size_t stride = (size_t)gridDim.x * 256 * 4;
  for (; i < N; i += stride) {
    float4 v = *(const float4*)(in + i);
    ushort4 o;
    o.x = f2bf(v.x); o.y = f2bf(v.y); o.z = f2bf(v.z); o.w = f2bf(v.w);
    *(ushort4*)(out + i) = o;
  }
}

// W1 f32 [p][8192][256] -> bf16 transposed chunk-local [z][256][8192]
__global__ void k_cvt_w1(const float* __restrict__ W1, unsigned short* __restrict__ out, int p0) {
  __shared__ unsigned short t[64][65];
  const int p = p0 + blockIdx.z;
  const float* src = W1 + (size_t)p * 8192 * 256;
  unsigned short* dst = out + (size_t)blockIdx.z * 256 * 8192;
  const int f0 = blockIdx.x * 64, h0 = blockIdx.y * 64;
#pragma unroll
  for (int i = 0; i < 16; ++i) {
    int tt = i * 256 + threadIdx.x;
    int r = tt >> 6, c = tt & 63;                      // r: f, c: h (coalesced f32 read)
    t[r][c] = f2bf(src[(size_t)(f0 + r) * 256 + h0 + c]);
  }
  __syncthreads();
#pragma unroll
  for (int i = 0; i < 4; ++i) {
    int tt = i * 256 + threadIdx.x;
    int r = tt >> 4;                                   // h row
    int c4 = (tt & 15) * 4;                            // f col group of 4
    ushort4 o;
    o.x = t[c4][r]; o.y = t[c4 + 1][r]; o.z = t[c4 + 2][r]; o.w = t[c4 + 3][r];
    *(ushort4*)&dst[(size_t)(h0 + r) * 8192 + f0 + c4] = o;
  }
}

// W2 f32 [p][256][128] -> bf16 transposed [p][128][256]
__global__ void k_cvt_w2(const float* __restrict__ W2, unsigned short* __restrict__ out) {
  const int p = blockIdx.x;
  const float* src = W2 + (size_t)p * 256 * 128;
  unsigned short* dst = out + (size_t)p * 128 * 256;
  for (int tt = threadIdx.x; tt < 128 * 256; tt += 256) {
    int j = tt >> 8, h = tt & 255;
    dst[tt] = f2bf(src[(size_t)h * 128 + j]);
  }
}

// ---------------- GEMM1: h1 = relu(features @ W1 + b1) ----------------
// OCCUPANCY-FIRST: 128x256 tile, BK=32, 8 waves (2Mx4N, per-wave 64x64,
// acc[4][4] ~115 VGPR), 3-buffer LDS ring 72 KiB -> 2 BLOCKS/CU (16 waves/CU,
// 4/SIMD). Cross-block overlap fills barrier/wait gaps (m114); depth-2
// counted prefetch covers HBM latency within a block.
//  tile t: stage(t+2): A 1 gload + B 2 gloads | 8 ds_read_b128 |
//          setprio(1) 16 MFMA setprio(0) | vmcnt(3) | BARRIER
// FIFO: before wait outstanding = {t+1:3, t+2:3}; vmcnt(3) retires t+1's,
// issued 2 tile-bodies earlier. Buffer (t+2)%3 hazard-free: its readers
// finished at the t-1 barrier.
// LDS row = 32 bf16 = 4 units of 16B; unit u of row r at phys u^((r>>1)&3)
// via pre-swizzled global source (rule 21); frag reads 2-way max (free).
__global__ __launch_bounds__(512, 4) void k_gemm1(
    const unsigned short* __restrict__ A,    // [4096][8192] bf16
    const unsigned short* __restrict__ Bt,   // [z][256][8192] bf16
    const float* __restrict__ b1,
    unsigned short* __restrict__ h1,
    int p0) {
  __shared__ __align__(16) unsigned short S[36864];  // 72 KiB: 3 x [A 4096 | B 8192] shorts

  const int tid = threadIdx.x;
  const int lane = tid & 63;
  const int wave = tid >> 6;
  const int wm = wave >> 2;   // 0..1 -> m half (64 rows)
  const int wn = wave & 3;    // 0..3 -> n quarter (64 cols)

  // bijective chunked XCD swizzle; z-major: consecutive wgs on an XCD share
  // predicate z -> B panel (4MB) L2-resident.
  const int nwg = gridDim.x * gridDim.y;
  const int orig = blockIdx.y * gridDim.x + blockIdx.x;
  const int q = nwg >> 3, r_ = nwg & 7;
  const int xcd = orig & 7, idx = orig >> 3;
  const int wg = (xcd < r_ ? xcd * (q + 1) : r_ * (q + 1) + (xcd - r_) * q) + idx;
  const int mx = wg & 31;     // gridDim.x == 32
  const int z = wg >> 5;
  const int p = p0 + z;
  const int m0 = mx * 128;

  const unsigned short* Ab = A + (size_t)m0 * 8192;
  const unsigned short* Bb = Bt + (size_t)z * 256 * 8192;

  // staging: unit e (16B): r=e>>2, phys=e&3, global unit u=(e&3)^((r>>1)&3)
  // A: 512 units (rows 0..127), thread covers e=tid.
  // B: 1024 units (rows 0..255), thread covers e0=tid, e1=512+tid.
  const int rA = tid >> 2, uA = (tid & 3) ^ ((rA >> 1) & 3);
  const int rB1 = 128 + (tid >> 2), uB1 = (tid & 3) ^ ((rB1 >> 1) & 3);
  const size_t sA = (size_t)rA * 8192 + uA * 8;       // also B round 0
  const size_t sB1 = (size_t)rB1 * 8192 + uB1 * 8;
  const int ld0 = wave * 512;                         // wave-uniform LDS short-offsets
  const int ld1 = 4096 + wave * 512;

  auto stage = [&](int buf, int T) {
    const size_t ko = (size_t)T * 32;
    unsigned short* lb = S + buf * 12288;
    gload16(Ab + sA + ko, lb + ld0);                  // A rows 0..127
    gload16(Bb + sA + ko, lb + 4096 + ld0);           // B rows 0..127
    gload16(Bb + sB1 + ko, lb + 4096 + ld1);          // B rows 128..255
  };

  const int l15 = lane & 15, ks = lane >> 4;

  auto rdA = [&](int buf, int mi) {
    int R = wm * 64 + mi * 16 + l15;
    int pu = ks ^ ((R >> 1) & 3);
    return __builtin_bit_cast(bf16x8, *(const short8_t*)(S + buf * 12288 + R * 32 + pu * 8));
  };
  auto rdB = [&](int buf, int nj) {
    int R = wn * 64 + nj * 16 + l15;
    int pu = ks ^ ((R >> 1) & 3);
    return __builtin_bit_cast(bf16x8, *(const short8_t*)(S + buf * 12288 + 4096 + R * 32 + pu * 8));
  };

  f32x4 acc[4][4] = {};
  const int NT = 8192 / 32;  // 256 K-tiles

  // prologue: tiles 0,1; retire tile 0's 3 loads (leave tile 1's 3 in flight)
  stage(0, 0);
  stage(1, 1);
  asm volatile("s_waitcnt vmcnt(3)" ::: "memory");
  BARRIER();

  int cur = 0, st = 2;
  for (int t = 0; t < NT; ++t) {
    if (t < NT - 2) stage(st, t + 2);
    bf16x8 af[4], bfv[4];
#pragma unroll
    for (int mi = 0; mi < 4; ++mi) af[mi] = rdA(cur, mi);
#pragma unroll
    for (int nj = 0; nj < 4; ++nj) bfv[nj] = rdB(cur, nj);
    __builtin_amdgcn_s_setprio(1);
#pragma unroll
    for (int mi = 0; mi < 4; ++mi)
#pragma unroll
      for (int nj = 0; nj < 4; ++nj)
        acc[mi][nj] = __builtin_amdgcn_mfma_f32_16x16x32_bf16(af[mi], bfv[nj], acc[mi][nj], 0, 0, 0);
    __builtin_amdgcn_s_setprio(0);
    if (t < NT - 2)       asm volatile("s_waitcnt vmcnt(3)" ::: "memory");
    else if (t == NT - 2) asm volatile("s_waitcnt vmcnt(0)" ::: "memory");
    BARRIER();
    cur = (cur == 2) ? 0 : cur + 1;
    st = (st == 2) ? 0 : st + 1;
  }

  // epilogue: + b1, relu, h1 bf16 [p][4096][256]
  const int rg = lane >> 4;
#pragma unroll
  for (int nj = 0; nj < 4; ++nj) {
    const int col = wn * 64 + nj * 16 + l15;
    const float bb = b1[p * 256 + col];
#pragma unroll
    for (int mi = 0; mi < 4; ++mi) {
      const int rbase = m0 + wm * 64 + mi * 16 + rg * 4;
#pragma unroll
      for (int rr = 0; rr < 4; ++rr) {
        float v = acc[mi][nj][rr] + bb;
        v = v > 0.f ? v : 0.f;
        h1[((size_t)p * 4096 + rbase + rr) * 256 + col] = f2bf(v);
      }
    }
  }
}

// ---------------- GEMM2+3 fused ----------------
__global__ __launch_bounds__(256, 2) void k_gemm23(
    const unsigned short* __restrict__ h1,   // [29][4096][256] bf16
    const unsigned short* __restrict__ W2t,  // [29][128][256] bf16
    const float* __restrict__ b2,
    const float* __restrict__ W3,
    const float* __restrict__ b3,
    float* __restrict__ out) {               // [4096][29]
  __shared__ __align__(16) unsigned short lds_a[128 * 64];
  __shared__ __align__(16) unsigned short lds_b[128 * 64];
  const int tid = threadIdx.x;
  const int lane = tid & 63;
  const int wave = tid >> 6;
  const int m0 = blockIdx.x * 128;
  const int p = blockIdx.y;

  const unsigned short* Ab = h1 + ((size_t)p * 4096 + m0) * 256;
  const unsigned short* Bb = W2t + (size_t)p * 128 * 256;

  f32x4 acc[2][8] = {};

  for (int k0 = 0; k0 < 256; k0 += 64) {
    __syncthreads();
#pragma unroll
    for (int i = 0; i < 4; ++i) {
      int t = i * 256 + tid;
      int r = t >> 3;
      int uu = (t & 7) ^ (r & 7);
      gload16(Ab + (size_t)r * 256 + k0 + uu * 8, &lds_a[(i * 256 + wave * 64) * 8]);
      gload16(Bb + (size_t)r * 256 + k0 + uu * 8, &lds_b[(i * 256 + wave * 64) * 8]);
    }
    __syncthreads();
#pragma unroll
    for (int kk = 0; kk < 64; kk += 32) {
      const int ku = (kk >> 3) + (lane >> 4);
      bf16x8 af[2], bfv[8];
#pragma unroll
      for (int mi = 0; mi < 2; ++mi) {
        int row = wave * 32 + mi * 16 + (lane & 15);
        int u = ku ^ (row & 7);
        af[mi] = __builtin_bit_cast(bf16x8, *(const short8_t*)&lds_a[row * 64 + u * 8]);
      }
#pragma unroll
      for (int nj = 0; nj < 8; ++nj) {
        int row = nj * 16 + (lane & 15);
        int u = ku ^ (row & 7);
        bfv[nj] = __builtin_bit_cast(bf16x8, *(const short8_t*)&lds_b[row * 64 + u * 8]);
      }
#pragma unroll
      for (int mi = 0; mi < 2; ++mi)
#pragma unroll
        for (int nj = 0; nj < 8; ++nj)
          acc[mi][nj] = __builtin_amdgcn_mfma_f32_16x16x32_bf16(af[mi], bfv[nj], acc[mi][nj], 0, 0, 0);
    }
  }

  float b2v[8], w3v[8];
  const int c16 = lane & 15;
#pragma unroll
  for (int nj = 0; nj < 8; ++nj) {
    int c = nj * 16 + c16;
    b2v[nj] = b2[p * 128 + c];
    w3v[nj] = W3[p * 128 + c];
  }
  const float b3p = b3[p];
#pragma unroll
  for (int mi = 0; mi < 2; ++mi) {
#pragma unroll
    for (int r = 0; r < 4; ++r) {
      float s = 0.f;
#pragma unroll
      for (int nj = 0; nj < 8; ++nj) {
        float v = acc[mi][nj][r] + b2v[nj];
        v = v > 0.f ? v : 0.f;
        s += v * w3v[nj];
      }
      s += __shfl_xor(s, 1);
      s += __shfl_xor(s, 2);
      s += __shfl_xor(s, 4);
      s += __shfl_xor(s, 8);
      if ((lane & 15) == 0) {
        int m = m0 + wave * 32 + mi * 16 + (lane >> 4) * 4 + r;
        float logit = s + b3p;
        out[(size_t)m * 29 + p] = 1.f / (1.f + __expf(-logit));
      }
    }
  }
}

// ---------------- launch ----------------
extern "C" void kernel_launch(void* const* d_in, const int* in_sizes, int n_in,
                              void* d_out, int out_size, void* d_ws, size_t ws_size,
                              hipStream_t stream) {
  const float* features = (const float*)d_in[0];
  const float* W1 = (const float*)d_in[1];
  const float* b1 = (const float*)d_in[2];
  const float* W2 = (const float*)d_in[3];
  const float* b2 = (const float*)d_in[4];
  const float* W3 = (const float*)d_in[5];
  const float* b3 = (const float*)d_in[6];
  float* out = (float*)d_out;

  char* ws = (char*)d_ws;
  const size_t featB = (size_t)4096 * 8192 * 2;       // 64 MB
  const size_t h1B   = (size_t)29 * 4096 * 256 * 2;   // 58 MB
  const size_t w2B   = (size_t)29 * 128 * 256 * 2;    // 1.9 MB
  const size_t w1pp  = (size_t)256 * 8192 * 2;        // 4 MB per predicate

  unsigned short* featbf = (unsigned short*)ws;
  unsigned short* h1bf   = (unsigned short*)(ws + featB);
  unsigned short* w2t    = (unsigned short*)(ws + featB + h1B);
  unsigned short* w1t    = (unsigned short*)(ws + featB + h1B + w2B);

  size_t base = featB + h1B + w2B;
  size_t rem = (ws_size > base) ? (ws_size - base) : 0;
  int CH = (int)(rem / w1pp);
  if (CH > 29) CH = 29;
  if (CH < 1) CH = 1;

  k_cvt_feat<<<2048, 256, 0, stream>>>(features, featbf);
  k_cvt_w2<<<29, 256, 0, stream>>>(W2, w2t);

  for (int p0 = 0; p0 < 29; p0 += CH) {
    int c = (29 - p0) < CH ? (29 - p0) : CH;
    k_cvt_w1<<<dim3(128, 4, c), 256, 0, stream>>>(W1, w1t, p0);
    k_gemm1<<<dim3(32, c), 512, 0, stream>>>(featbf, w1t, b1, h1bf, p0);
  }

  k_gemm23<<<dim3(32, 29), 256, 0, stream>>>(h1bf, w2t, b2, W3, b3, out);
}

// Round 8
// 604.978 us; speedup vs baseline: 1.0625x; 1.0625x over previous
//
#include <hip/hip_runtime.h>
#include <hip/hip_bf16.h>

typedef __attribute__((ext_vector_type(8))) short short8_t;
typedef __attribute__((ext_vector_type(8))) __bf16 bf16x8;
typedef __attribute__((ext_vector_type(4))) float f32x4;
typedef __attribute__((ext_vector_type(16))) float f32x16;

__device__ __forceinline__ void gload16(const void* g, void* l) {
  __builtin_amdgcn_global_load_lds(
      (const __attribute__((address_space(1))) void*)g,
      (__attribute__((address_space(3))) void*)l, 16, 0, 0);
}

__device__ __forceinline__ unsigned short f2bf(float f) {
  __hip_bfloat16 h = __float2bfloat16(f);
  return __builtin_bit_cast(unsigned short, h);
}

#define BARRIER() asm volatile("s_barrier" ::: "memory")

// ---------------- conversion kernels ----------------

__global__ void k_cvt_feat(const float* __restrict__ in, unsigned short* __restrict__ out) {
  const size_t N = (size_t)4096 * 8192;
  size_t i = ((size_t)blockIdx.x * 256 + threadIdx.x) * 4;
  const size_t stride = (size_t)gridDim.x * 256 * 4;
  for (; i < N; i += stride) {
    float4 v = *(const float4*)(in + i);
    ushort4 o;
    o.x = f2bf(v.x); o.y = f2bf(v.y); o.z = f2bf(v.z); o.w = f2bf(v.w);
    *(ushort4*)(out + i) = o;
  }
}

// W1 f32 [p][8192][256] -> bf16 transposed chunk-local [z][256][8192]
__global__ void k_cvt_w1(const float* __restrict__ W1, unsigned short* __restrict__ out, int p0) {
  __shared__ unsigned short t[64][65];
  const int p = p0 + blockIdx.z;
  const float* src = W1 + (size_t)p * 8192 * 256;
  unsigned short* dst = out + (size_t)blockIdx.z * 256 * 8192;
  const int f0 = blockIdx.x * 64, h0 = blockIdx.y * 64;
#pragma unroll
  for (int i = 0; i < 16; ++i) {
    int tt = i * 256 + threadIdx.x;
    int r = tt >> 6, c = tt & 63;
    t[r][c] = f2bf(src[(size_t)(f0 + r) * 256 + h0 + c]);
  }
  __syncthreads();
#pragma unroll
  for (int i = 0; i < 4; ++i) {
    int tt = i * 256 + threadIdx.x;
    int r = tt >> 4;
    int c4 = (tt & 15) * 4;
    ushort4 o;
    o.x = t[c4][r]; o.y = t[c4 + 1][r]; o.z = t[c4 + 2][r]; o.w = t[c4 + 3][r];
    *(ushort4*)&dst[(size_t)(h0 + r) * 8192 + f0 + c4] = o;
  }
}

// W2 f32 [p][256][128] -> bf16 transposed [p][128][256]
__global__ void k_cvt_w2(const float* __restrict__ W2, unsigned short* __restrict__ out) {
  const int p = blockIdx.x;
  const float* src = W2 + (size_t)p * 256 * 128;
  unsigned short* dst = out + (size_t)p * 128 * 256;
  for (int tt = threadIdx.x; tt < 128 * 256; tt += 256) {
    int j = tt >> 8, h = tt & 255;
    dst[tt] = f2bf(src[(size_t)h * 128 + j]);
  }
}

// ---------------- GEMM1: h1 = relu(features @ W1 + b1) ----------------
// Round-5 structure (453us champion) with 32x32x16 MFMA (2382 vs 2075 TF
// ceiling, half the MFMA issues). 256x256 tile, BK=64, 8 waves; per phase
// all 8 waves compute ONE 128x128 C-quadrant; wave sub-block 64(M)x32(N)
// = 2 m-frags (32 rows) x 1 n-frag (32 cols) x 4 k-steps = 8 MFMA/phase.
//  ph1: read aF(h0: 8 b128)+bL(v0: 4) | BAR | MFMA Q00 | BAR
//  ph2: read bH(v1: 4)   | stage A0(t+2)        | BAR | MFMA Q01 | BAR
//  ph3: read aF(h1: 8)   | stage B1(t+2)        | BAR | MFMA Q10 | BAR
//  ph4:                  | stage B0,A1(t+2)     | MFMA Q11 | vmcnt(8) | BAR
// vmcnt(8) retires tile t+1's 8 loads (issued >=4 phases earlier); t+2's 8
// stay in flight. LDS layout/staging/swizzle identical to round 5.
__global__ __launch_bounds__(512, 2) void k_gemm1(
    const unsigned short* __restrict__ A,    // [4096][8192] bf16
    const unsigned short* __restrict__ Bt,   // [z][256][8192] bf16
    const float* __restrict__ b1,
    unsigned short* __restrict__ h1,
    int p0) {
  __shared__ __align__(16) unsigned short S[65536];  // 128 KiB

  const int tid = threadIdx.x;
  const int lane = tid & 63;
  const int wave = tid >> 6;
  const int sr = (wave >> 2) * 64;   // sub-rows within 128-row half
  const int sc = (wave & 3) * 32;    // sub-cols within 128-col half

  // bijective chunked XCD swizzle; z-major: 16 consecutive wgs per XCD share
  // predicate z -> B panel L2-resident.
  const int nwg = gridDim.x * gridDim.y;
  const int orig = blockIdx.y * gridDim.x + blockIdx.x;
  const int q = nwg >> 3, r_ = nwg & 7;
  const int xcd = orig & 7, idx = orig >> 3;
  const int wg = (xcd < r_ ? xcd * (q + 1) : r_ * (q + 1) + (xcd - r_) * q) + idx;
  const int mx = wg & 15;     // gridDim.x == 16
  const int z = wg >> 4;
  const int p = p0 + z;
  const int m0 = mx * 256;

  const unsigned short* Ab = A + (size_t)m0 * 8192;
  const unsigned short* Bb = Bt + (size_t)z * 256 * 8192;

  // staging: half = [128 rows][8 units of 16B]; e=i*512+tid; r=e>>3,
  // phys unit=e&7, global unit=(e&7)^(r&7)
  int e0 = tid, r0 = e0 >> 3, u0 = (e0 & 7) ^ (r0 & 7);
  int e1 = 512 + tid, r1e = e1 >> 3, u1 = (e1 & 7) ^ (r1e & 7);
  const size_t s0 = (size_t)r0 * 8192 + u0 * 8;
  const size_t s1 = (size_t)r1e * 8192 + u1 * 8;
  const int ld0 = (wave * 64) * 8;
  const int ld1 = (512 + wave * 64) * 8;

  auto stage = [&](int buf, int isB, int h, int T) {
    const unsigned short* gb = (isB ? Bb : Ab) + (size_t)h * 128 * 8192 + (size_t)T * 64;
    unsigned short* lb = S + buf * 32768 + isB * 16384 + h * 8192;
    gload16(gb + s0, lb + ld0);
    gload16(gb + s1, lb + ld1);
  };

  const int l31 = lane & 31, ks2 = lane >> 5;

  // A frag (mfma 32x32x16): row = l31, k = ks2*8 + j; kx = k-step 0..3
  auto rdA = [&](int buf, int h, int mi, int kx) {
    int R = sr + mi * 32 + l31;
    int pu = (kx * 2 + ks2) ^ (R & 7);
    return __builtin_bit_cast(bf16x8, *(const short8_t*)(S + buf * 32768 + h * 8192 + R * 64 + pu * 8));
  };
  auto rdB = [&](int buf, int v, int kx) {
    int R = sc + l31;
    int pu = (kx * 2 + ks2) ^ (R & 7);
    return __builtin_bit_cast(bf16x8, *(const short8_t*)(S + buf * 32768 + 16384 + v * 8192 + R * 64 + pu * 8));
  };

  f32x16 acc[4][2] = {};     // [quadrant qh*2+qv][mi]
  const int NT = 8192 / 64;  // 128 K-tiles

  auto kstep = [&](int t, int pf, int vm) {
    const int c = t & 1;
    bf16x8 aF[2][4], bL[4], bH[4];
    // ---- ph1: Q00 ----
#pragma unroll
    for (int mi = 0; mi < 2; ++mi)
#pragma unroll
      for (int kx = 0; kx < 4; ++kx) aF[mi][kx] = rdA(c, 0, mi, kx);
#pragma unroll
    for (int kx = 0; kx < 4; ++kx) bL[kx] = rdB(c, 0, kx);
    BARRIER();
    __builtin_amdgcn_s_setprio(1);
#pragma unroll
    for (int kx = 0; kx < 4; ++kx)
#pragma unroll
      for (int mi = 0; mi < 2; ++mi)
        acc[0][mi] = __builtin_amdgcn_mfma_f32_32x32x16_bf16(aF[mi][kx], bL[kx], acc[0][mi], 0, 0, 0);
    __builtin_amdgcn_s_setprio(0);
    BARRIER();
    // ---- ph2: Q01 (reuse aF); stage A0(t+2) ----
#pragma unroll
    for (int kx = 0; kx < 4; ++kx) bH[kx] = rdB(c, 1, kx);
    if (pf) stage(c, 0, 0, t + 2);
    BARRIER();
    __builtin_amdgcn_s_setprio(1);
#pragma unroll
    for (int kx = 0; kx < 4; ++kx)
#pragma unroll
      for (int mi = 0; mi < 2; ++mi)
        acc[1][mi] = __builtin_amdgcn_mfma_f32_32x32x16_bf16(aF[mi][kx], bH[kx], acc[1][mi], 0, 0, 0);
    __builtin_amdgcn_s_setprio(0);
    BARRIER();
    // ---- ph3: Q10 (reuse bL); stage B1(t+2) ----
#pragma unroll
    for (int mi = 0; mi < 2; ++mi)
#pragma unroll
      for (int kx = 0; kx < 4; ++kx) aF[mi][kx] = rdA(c, 1, mi, kx);
    if (pf) stage(c, 1, 1, t + 2);
    BARRIER();
    __builtin_amdgcn_s_setprio(1);
#pragma unroll
    for (int kx = 0; kx < 4; ++kx)
#pragma unroll
      for (int mi = 0; mi < 2; ++mi)
        acc[2][mi] = __builtin_amdgcn_mfma_f32_32x32x16_bf16(aF[mi][kx], bL[kx], acc[2][mi], 0, 0, 0);
    __builtin_amdgcn_s_setprio(0);
    BARRIER();
    // ---- ph4: Q11 (reuse aF, bH); stage B0,A1(t+2); counted wait ----
    if (pf) { stage(c, 1, 0, t + 2); stage(c, 0, 1, t + 2); }
    __builtin_amdgcn_s_setprio(1);
#pragma unroll
    for (int kx = 0; kx < 4; ++kx)
#pragma unroll
      for (int mi = 0; mi < 2; ++mi)
        acc[3][mi] = __builtin_amdgcn_mfma_f32_32x32x16_bf16(aF[mi][kx], bH[kx], acc[3][mi], 0, 0, 0);
    __builtin_amdgcn_s_setprio(0);
    if (vm == 8)      asm volatile("s_waitcnt vmcnt(8)" ::: "memory");
    else if (vm == 0) asm volatile("s_waitcnt vmcnt(0)" ::: "memory");
    BARRIER();
  };

  // prologue: tile0 {A0,B0,B1,A1}, tile1 steady-state order {A0,B1,B0,A1}
  stage(0, 0, 0, 0); stage(0, 1, 0, 0); stage(0, 1, 1, 0); stage(0, 0, 1, 0);
  stage(1, 0, 0, 1); stage(1, 1, 1, 1); stage(1, 1, 0, 1); stage(1, 0, 1, 1);
  asm volatile("s_waitcnt vmcnt(8)" ::: "memory");
  BARRIER();

  for (int t = 0; t < NT - 2; ++t) kstep(t, 1, 8);
  kstep(NT - 2, 0, 0);
  kstep(NT - 1, 0, -1);

  // epilogue: + b1, relu, h1 bf16 [p][4096][256]
  // C/D 32x32 layout: col=lane&31, row=(reg&3)+8*(reg>>2)+4*(lane>>5)
#pragma unroll
  for (int qh = 0; qh < 2; ++qh)
#pragma unroll
    for (int qv = 0; qv < 2; ++qv) {
      const int qq = qh * 2 + qv;
      const int col = qv * 128 + sc + l31;
      const float bb = b1[p * 256 + col];
#pragma unroll
      for (int mi = 0; mi < 2; ++mi) {
        const int rbase = m0 + qh * 128 + sr + mi * 32 + 4 * ks2;
#pragma unroll
        for (int rg = 0; rg < 16; ++rg) {
          const int row = rbase + (rg & 3) + 8 * (rg >> 2);
          float v = acc[qq][mi][rg] + bb;
          v = v > 0.f ? v : 0.f;
          h1[((size_t)p * 4096 + row) * 256 + col] = f2bf(v);
        }
      }
    }
}

// ---------------- GEMM2+3 fused ----------------
__global__ __launch_bounds__(256, 2) void k_gemm23(
    const unsigned short* __restrict__ h1,   // [29][4096][256] bf16
    const unsigned short* __restrict__ W2t,  // [29][128][256] bf16
    const float* __restrict__ b2,
    const float* __restrict__ W3,
    const float* __restrict__ b3,
    float* __restrict__ out) {               // [4096][29]
  __shared__ __align__(16) unsigned short lds_a[128 * 64];
  __shared__ __align__(16) unsigned short lds_b[128 * 64];
  const int tid = threadIdx.x;
  const int lane = tid & 63;
  const int wave = tid >> 6;
  const int m0 = blockIdx.x * 128;
  const int p = blockIdx.y;

  const unsigned short* Ab = h1 + ((size_t)p * 4096 + m0) * 256;
  const unsigned short* Bb = W2t + (size_t)p * 128 * 256;

  f32x4 acc[2][8] = {};

  for (int k0 = 0; k0 < 256; k0 += 64) {
    __syncthreads();
#pragma unroll
    for (int i = 0; i < 4; ++i) {
      int t = i * 256 + tid;
      int r = t >> 3;
      int uu = (t & 7) ^ (r & 7);
      gload16(Ab + (size_t)r * 256 + k0 + uu * 8, &lds_a[(i * 256 + wave * 64) * 8]);
      gload16(Bb + (size_t)r * 256 + k0 + uu * 8, &lds_b[(i * 256 + wave * 64) * 8]);
    }
    __syncthreads();
#pragma unroll
    for (int kk = 0; kk < 64; kk += 32) {
      const int ku = (kk >> 3) + (lane >> 4);
      bf16x8 af[2], bfv[8];
#pragma unroll
      for (int mi = 0; mi < 2; ++mi) {
        int row = wave * 32 + mi * 16 + (lane & 15);
        int u = ku ^ (row & 7);
        af[mi] = __builtin_bit_cast(bf16x8, *(const short8_t*)&lds_a[row * 64 + u * 8]);
      }
#pragma unroll
      for (int nj = 0; nj < 8; ++nj) {
        int row = nj * 16 + (lane & 15);
        int u = ku ^ (row & 7);
        bfv[nj] = __builtin_bit_cast(bf16x8, *(const short8_t*)&lds_b[row * 64 + u * 8]);
      }
#pragma unroll
      for (int mi = 0; mi < 2; ++mi)
#pragma unroll
        for (int nj = 0; nj < 8; ++nj)
          acc[mi][nj] = __builtin_amdgcn_mfma_f32_16x16x32_bf16(af[mi], bfv[nj], acc[mi][nj], 0, 0, 0);
    }
  }

  float b2v[8], w3v[8];
  const int c16 = lane & 15;
#pragma unroll
  for (int nj = 0; nj < 8; ++nj) {
    int c = nj * 16 + c16;
    b2v[nj] = b2[p * 128 + c];
    w3v[nj] = W3[p * 128 + c];
  }
  const float b3p = b3[p];
#pragma unroll
  for (int mi = 0; mi < 2; ++mi) {
#pragma unroll
    for (int r = 0; r < 4; ++r) {
      float s = 0.f;
#pragma unroll
      for (int nj = 0; nj < 8; ++nj) {
        float v = acc[mi][nj][r] + b2v[nj];
        v = v > 0.f ? v : 0.f;
        s += v * w3v[nj];
      }
      s += __shfl_xor(s, 1);
      s += __shfl_xor(s, 2);
      s += __shfl_xor(s, 4);
      s += __shfl_xor(s, 8);
      if ((lane & 15) == 0) {
        int m = m0 + wave * 32 + mi * 16 + (lane >> 4) * 4 + r;
        float logit = s + b3p;
        out[(size_t)m * 29 + p] = 1.f / (1.f + __expf(-logit));
      }
    }
  }
}

// ---------------- launch ----------------
extern "C" void kernel_launch(void* const* d_in, const int* in_sizes, int n_in,
                              void* d_out, int out_size, void* d_ws, size_t ws_size,
                              hipStream_t stream) {
  const float* features = (const float*)d_in[0];
  const float* W1 = (const float*)d_in[1];
  const float* b1 = (const float*)d_in[2];
  const float* W2 = (const float*)d_in[3];
  const float* b2 = (const float*)d_in[4];
  const float* W3 = (const float*)d_in[5];
  const float* b3 = (const float*)d_in[6];
  float* out = (float*)d_out;

  char* ws = (char*)d_ws;
  const size_t featB = (size_t)4096 * 8192 * 2;       // 64 MB
  const size_t h1B   = (size_t)29 * 4096 * 256 * 2;   // 58 MB
  const size_t w2B   = (size_t)29 * 128 * 256 * 2;    // 1.9 MB
  const size_t w1pp  = (size_t)256 * 8192 * 2;        // 4 MB per predicate

  unsigned short* featbf = (unsigned short*)ws;
  unsigned short* h1bf   = (unsigned short*)(ws + featB);
  unsigned short* w2t    = (unsigned short*)(ws + featB + h1B);
  unsigned short* w1t    = (unsigned short*)(ws + featB + h1B + w2B);

  size_t base = featB + h1B + w2B;
  size_t rem = (ws_size > base) ? (ws_size - base) : 0;
  int CH = (int)(rem / w1pp);
  if (CH > 29) CH = 29;
  if (CH < 1) CH = 1;

  k_cvt_feat<<<2048, 256, 0, stream>>>(features, featbf);
  k_cvt_w2<<<29, 256, 0, stream>>>(W2, w2t);

  for (int p0 = 0; p0 < 29; p0 += CH) {
    int c = (29 - p0) < CH ? (29 - p0) : CH;
    k_cvt_w1<<<dim3(128, 4, c), 256, 0, stream>>>(W1, w1t, p0);
    k_gemm1<<<dim3(16, c), 512, 0, stream>>>(featbf, w1t, b1, h1bf, p0);
  }

  k_gemm23<<<dim3(32, 29), 256, 0, stream>>>(h1bf, w2t, b2, W3, b3, out);
}

// Round 9
// 540.230 us; speedup vs baseline: 1.1898x; 1.1199x over previous
//
#include <hip/hip_runtime.h>
#include <hip/hip_bf16.h>

typedef __attribute__((ext_vector_type(8))) short short8_t;
typedef __attribute__((ext_vector_type(8))) __bf16 bf16x8;
typedef __attribute__((ext_vector_type(4))) float f32x4;

__device__ __forceinline__ void gload16(const void* g, void* l) {
  __builtin_amdgcn_global_load_lds(
      (const __attribute__((address_space(1))) void*)g,
      (__attribute__((address_space(3))) void*)l, 16, 0, 0);
}

__device__ __forceinline__ unsigned short f2bf(float f) {
  __hip_bfloat16 h = __float2bfloat16(f);
  return __builtin_bit_cast(unsigned short, h);
}

#define BARRIER() asm volatile("s_barrier" ::: "memory")

// ---------------- conversion kernels ----------------

__global__ void k_cvt_feat(const float* __restrict__ in, unsigned short* __restrict__ out) {
  const size_t N = (size_t)4096 * 8192;
  size_t i = ((size_t)blockIdx.x * 256 + threadIdx.x) * 4;
  const size_t stride = (size_t)gridDim.x * 256 * 4;
  for (; i < N; i += stride) {
    float4 v = *(const float4*)(in + i);
    ushort4 o;
    o.x = f2bf(v.x); o.y = f2bf(v.y); o.z = f2bf(v.z); o.w = f2bf(v.w);
    *(ushort4*)(out + i) = o;
  }
}

// W1 f32 [p][8192][256] -> bf16 transposed chunk-local [z][256][8192]
__global__ void k_cvt_w1(const float* __restrict__ W1, unsigned short* __restrict__ out, int p0) {
  __shared__ unsigned short t[64][65];
  const int p = p0 + blockIdx.z;
  const float* src = W1 + (size_t)p * 8192 * 256;
  unsigned short* dst = out + (size_t)blockIdx.z * 256 * 8192;
  const int f0 = blockIdx.x * 64, h0 = blockIdx.y * 64;
#pragma unroll
  for (int i = 0; i < 16; ++i) {
    int tt = i * 256 + threadIdx.x;
    int r = tt >> 6, c = tt & 63;
    t[r][c] = f2bf(src[(size_t)(f0 + r) * 256 + h0 + c]);
  }
  __syncthreads();
#pragma unroll
  for (int i = 0; i < 4; ++i) {
    int tt = i * 256 + threadIdx.x;
    int r = tt >> 4;
    int c4 = (tt & 15) * 4;
    ushort4 o;
    o.x = t[c4][r]; o.y = t[c4 + 1][r]; o.z = t[c4 + 2][r]; o.w = t[c4 + 3][r];
    *(ushort4*)&dst[(size_t)(h0 + r) * 8192 + f0 + c4] = o;
  }
}

// W2 f32 [p][256][128] -> bf16 transposed [p][128][256]
__global__ void k_cvt_w2(const float* __restrict__ W2, unsigned short* __restrict__ out) {
  const int p = blockIdx.x;
  const float* src = W2 + (size_t)p * 256 * 128;
  unsigned short* dst = out + (size_t)p * 128 * 256;
  for (int tt = threadIdx.x; tt < 128 * 256; tt += 256) {
    int j = tt >> 8, h = tt & 255;
    dst[tt] = f2bf(src[(size_t)h * 128 + j]);
  }
}

// ---------------- GEMM1: h1 = relu(features @ W1 + b1) ----------------
// Round-5 16x16x32 quadrant structure (453us, 0 conflicts) with m201-style
// smoothed staging: ONE half-tile per phase, ONE counted vmcnt(6)/K-tile.
//  ph1: read A-h0(8 b128)+B-v0(4) | stage A1(t+1)->buf nx | BAR | MFMA Q00 | BAR
//  ph2: read B-v1(4)              | stage A0(t+2)->buf c  | BAR | MFMA Q01 | BAR
//  ph3: read A-h1(8)              | stage B1(t+2)->buf c  | BAR | MFMA Q10 | BAR
//  ph4:                           | stage B0(t+2)->buf c  | MFMA Q11 | vmcnt(6) | BAR
// Slot hazards: A1(nx) last read ph3(t-1); A0(c) ph1(t); B1(c) ph2(t); B0(c)
// ph1(t) -- each stage is >=1 barrier after its slot's last read.
// FIFO (2 loads/half): after each tile's wait, outstanding = {A0,B1,B0}(t+2)
// = 6 loads; vmcnt(6) retires all 4 halves of tile t+1 (youngest A1(t+1)
// issued ph1(t), 3 phases before the wait).
__global__ __launch_bounds__(512, 2) void k_gemm1(
    const unsigned short* __restrict__ A,    // [4096][8192] bf16
    const unsigned short* __restrict__ Bt,   // [z][256][8192] bf16
    const float* __restrict__ b1,
    unsigned short* __restrict__ h1,
    int p0) {
  __shared__ __align__(16) unsigned short S[65536];  // 128 KiB

  const int tid = threadIdx.x;
  const int lane = tid & 63;
  const int wave = tid >> 6;
  const int sr = (wave >> 2) * 64;   // sub-rows within 128-row half
  const int sc = (wave & 3) * 32;    // sub-cols within 128-col half

  // bijective chunked XCD swizzle; z-major: 16 consecutive wgs per XCD share
  // predicate z -> B panel L2-resident.
  const int nwg = gridDim.x * gridDim.y;
  const int orig = blockIdx.y * gridDim.x + blockIdx.x;
  const int q = nwg >> 3, r_ = nwg & 7;
  const int xcd = orig & 7, idx = orig >> 3;
  const int wg = (xcd < r_ ? xcd * (q + 1) : r_ * (q + 1) + (xcd - r_) * q) + idx;
  const int mx = wg & 15;     // gridDim.x == 16
  const int z = wg >> 4;
  const int p = p0 + z;
  const int m0 = mx * 256;

  const unsigned short* Ab = A + (size_t)m0 * 8192;
  const unsigned short* Bb = Bt + (size_t)z * 256 * 8192;

  // staging: half = [128 rows][8 units of 16B]; e=i*512+tid; r=e>>3,
  // phys unit=e&7, global unit=(e&7)^(r&7)
  int e0 = tid, r0 = e0 >> 3, u0 = (e0 & 7) ^ (r0 & 7);
  int e1 = 512 + tid, r1e = e1 >> 3, u1 = (e1 & 7) ^ (r1e & 7);
  const size_t s0 = (size_t)r0 * 8192 + u0 * 8;
  const size_t s1 = (size_t)r1e * 8192 + u1 * 8;
  const int ld0 = (wave * 64) * 8;
  const int ld1 = (512 + wave * 64) * 8;

  auto stage = [&](int buf, int isB, int h, int T) {
    const unsigned short* gb = (isB ? Bb : Ab) + (size_t)h * 128 * 8192 + (size_t)T * 64;
    unsigned short* lb = S + buf * 32768 + isB * 16384 + h * 8192;
    gload16(gb + s0, lb + ld0);
    gload16(gb + s1, lb + ld1);
  };

  const int l15 = lane & 15, ks = lane >> 4;

  auto rdA = [&](int buf, int h, int mi, int x) {
    int R = sr + mi * 16 + l15;
    int pu = (x * 4 + ks) ^ (R & 7);
    return __builtin_bit_cast(bf16x8, *(const short8_t*)(S + buf * 32768 + h * 8192 + R * 64 + pu * 8));
  };
  auto rdB = [&](int buf, int v, int nj, int x) {
    int R = sc + nj * 16 + l15;
    int pu = (x * 4 + ks) ^ (R & 7);
    return __builtin_bit_cast(bf16x8, *(const short8_t*)(S + buf * 32768 + 16384 + v * 8192 + R * 64 + pu * 8));
  };

  f32x4 acc[4][4][2] = {};   // [quadrant q=h*2+v][mi][nj]
  const int NT = 8192 / 64;  // 128 K-tiles

  auto kstep = [&](int t, int pfa, int pf, int vm) {
    const int c = t & 1, nx = c ^ 1;
    bf16x8 a[4][2], bl[2][2], bh[2][2];
    // ---- ph1: Q00; stage A1(t+1) ----
#pragma unroll
    for (int mi = 0; mi < 4; ++mi) { a[mi][0] = rdA(c, 0, mi, 0); a[mi][1] = rdA(c, 0, mi, 1); }
#pragma unroll
    for (int nj = 0; nj < 2; ++nj) { bl[nj][0] = rdB(c, 0, nj, 0); bl[nj][1] = rdB(c, 0, nj, 1); }
    if (pfa) stage(nx, 0, 1, t + 1);
    BARRIER();
    __builtin_amdgcn_s_setprio(1);
#pragma unroll
    for (int mi = 0; mi < 4; ++mi)
#pragma unroll
      for (int nj = 0; nj < 2; ++nj) {
        acc[0][mi][nj] = __builtin_amdgcn_mfma_f32_16x16x32_bf16(a[mi][0], bl[nj][0], acc[0][mi][nj], 0, 0, 0);
        acc[0][mi][nj] = __builtin_amdgcn_mfma_f32_16x16x32_bf16(a[mi][1], bl[nj][1], acc[0][mi][nj], 0, 0, 0);
      }
    __builtin_amdgcn_s_setprio(0);
    BARRIER();
    // ---- ph2: Q01 (reuse a); stage A0(t+2) ----
#pragma unroll
    for (int nj = 0; nj < 2; ++nj) { bh[nj][0] = rdB(c, 1, nj, 0); bh[nj][1] = rdB(c, 1, nj, 1); }
    if (pf) stage(c, 0, 0, t + 2);
    BARRIER();
    __builtin_amdgcn_s_setprio(1);
#pragma unroll
    for (int mi = 0; mi < 4; ++mi)
#pragma unroll
      for (int nj = 0; nj < 2; ++nj) {
        acc[1][mi][nj] = __builtin_amdgcn_mfma_f32_16x16x32_bf16(a[mi][0], bh[nj][0], acc[1][mi][nj], 0, 0, 0);
        acc[1][mi][nj] = __builtin_amdgcn_mfma_f32_16x16x32_bf16(a[mi][1], bh[nj][1], acc[1][mi][nj], 0, 0, 0);
      }
    __builtin_amdgcn_s_setprio(0);
    BARRIER();
    // ---- ph3: Q10 (reuse bl); stage B1(t+2) ----
#pragma unroll
    for (int mi = 0; mi < 4; ++mi) { a[mi][0] = rdA(c, 1, mi, 0); a[mi][1] = rdA(c, 1, mi, 1); }
    if (pf) stage(c, 1, 1, t + 2);
    BARRIER();
    __builtin_amdgcn_s_setprio(1);
#pragma unroll
    for (int mi = 0; mi < 4; ++mi)
#pragma unroll
      for (int nj = 0; nj < 2; ++nj) {
        acc[2][mi][nj] = __builtin_amdgcn_mfma_f32_16x16x32_bf16(a[mi][0], bl[nj][0], acc[2][mi][nj], 0, 0, 0);
        acc[2][mi][nj] = __builtin_amdgcn_mfma_f32_16x16x32_bf16(a[mi][1], bl[nj][1], acc[2][mi][nj], 0, 0, 0);
      }
    __builtin_amdgcn_s_setprio(0);
    BARRIER();
    // ---- ph4: Q11 (reuse a, bh); stage B0(t+2); counted wait ----
    if (pf) stage(c, 1, 0, t + 2);
    __builtin_amdgcn_s_setprio(1);
#pragma unroll
    for (int mi = 0; mi < 4; ++mi)
#pragma unroll
      for (int nj = 0; nj < 2; ++nj) {
        acc[3][mi][nj] = __builtin_amdgcn_mfma_f32_16x16x32_bf16(a[mi][0], bh[nj][0], acc[3][mi][nj], 0, 0, 0);
        acc[3][mi][nj] = __builtin_amdgcn_mfma_f32_16x16x32_bf16(a[mi][1], bh[nj][1], acc[3][mi][nj], 0, 0, 0);
      }
    __builtin_amdgcn_s_setprio(0);
    if (vm == 6)      asm volatile("s_waitcnt vmcnt(6)" ::: "memory");
    else if (vm == 0) asm volatile("s_waitcnt vmcnt(0)" ::: "memory");
    BARRIER();
  };

  // prologue: tile0 all 4 halves {A0,B0,B1,A1}, tile1 {A0,B1,B0} (A1(1) comes
  // at ph1(0)); vmcnt(6) retires exactly tile0's 8 loads.
  stage(0, 0, 0, 0); stage(0, 1, 0, 0); stage(0, 1, 1, 0); stage(0, 0, 1, 0);
  stage(1, 0, 0, 1); stage(1, 1, 1, 1); stage(1, 1, 0, 1);
  asm volatile("s_waitcnt vmcnt(6)" ::: "memory");
  BARRIER();

  for (int t = 0; t < NT - 2; ++t) kstep(t, 1, 1, 6);
  kstep(NT - 2, 1, 0, 0);
  kstep(NT - 1, 0, 0, -1);

  // epilogue: + b1, relu, h1 bf16 [p][4096][256]
  const int rg = lane >> 4;
#pragma unroll
  for (int qh = 0; qh < 2; ++qh)
#pragma unroll
    for (int qv = 0; qv < 2; ++qv) {
      const int qq = qh * 2 + qv;
#pragma unroll
      for (int nj = 0; nj < 2; ++nj) {
        const int col = qv * 128 + sc + nj * 16 + l15;
        const float bb = b1[p * 256 + col];
#pragma unroll
        for (int mi = 0; mi < 4; ++mi) {
          const int rbase = m0 + qh * 128 + sr + mi * 16 + rg * 4;
#pragma unroll
          for (int rr = 0; rr < 4; ++rr) {
            float v = acc[qq][mi][nj][rr] + bb;
            v = v > 0.f ? v : 0.f;
            h1[((size_t)p * 4096 + rbase + rr) * 256 + col] = f2bf(v);
          }
        }
      }
    }
}

// ---------------- GEMM2+3 fused ----------------
__global__ __launch_bounds__(256, 2) void k_gemm23(
    const unsigned short* __restrict__ h1,   // [29][4096][256] bf16
    const unsigned short* __restrict__ W2t,  // [29][128][256] bf16
    const float* __restrict__ b2,
    const float* __restrict__ W3,
    const float* __restrict__ b3,
    float* __restrict__ out) {               // [4096][29]
  __shared__ __align__(16) unsigned short lds_a[128 * 64];
  __shared__ __align__(16) unsigned short lds_b[128 * 64];
  const int tid = threadIdx.x;
  const int lane = tid & 63;
  const int wave = tid >> 6;
  const int m0 = blockIdx.x * 128;
  const int p = blockIdx.y;

  const unsigned short* Ab = h1 + ((size_t)p * 4096 + m0) * 256;
  const unsigned short* Bb = W2t + (size_t)p * 128 * 256;

  f32x4 acc[2][8] = {};

  for (int k0 = 0; k0 < 256; k0 += 64) {
    __syncthreads();
#pragma unroll
    for (int i = 0; i < 4; ++i) {
      int t = i * 256 + tid;
      int r = t >> 3;
      int uu = (t & 7) ^ (r & 7);
      gload16(Ab + (size_t)r * 256 + k0 + uu * 8, &lds_a[(i * 256 + wave * 64) * 8]);
      gload16(Bb + (size_t)r * 256 + k0 + uu * 8, &lds_b[(i * 256 + wave * 64) * 8]);
    }
    __syncthreads();
#pragma unroll
    for (int kk = 0; kk < 64; kk += 32) {
      const int ku = (kk >> 3) + (lane >> 4);
      bf16x8 af[2], bfv[8];
#pragma unroll
      for (int mi = 0; mi < 2; ++mi) {
        int row = wave * 32 + mi * 16 + (lane & 15);
        int u = ku ^ (row & 7);
        af[mi] = __builtin_bit_cast(bf16x8, *(const short8_t*)&lds_a[row * 64 + u * 8]);
      }
#pragma unroll
      for (int nj = 0; nj < 8; ++nj) {
        int row = nj * 16 + (lane & 15);
        int u = ku ^ (row & 7);
        bfv[nj] = __builtin_bit_cast(bf16x8, *(const short8_t*)&lds_b[row * 64 + u * 8]);
      }
#pragma unroll
      for (int mi = 0; mi < 2; ++mi)
#pragma unroll
        for (int nj = 0; nj < 8; ++nj)
          acc[mi][nj] = __builtin_amdgcn_mfma_f32_16x16x32_bf16(af[mi], bfv[nj], acc[mi][nj], 0, 0, 0);
    }
  }

  float b2v[8], w3v[8];
  const int c16 = lane & 15;
#pragma unroll
  for (int nj = 0; nj < 8; ++nj) {
    int c = nj * 16 + c16;
    b2v[nj] = b2[p * 128 + c];
    w3v[nj] = W3[p * 128 + c];
  }
  const float b3p = b3[p];
#pragma unroll
  for (int mi = 0; mi < 2; ++mi) {
#pragma unroll
    for (int r = 0; r < 4; ++r) {
      float s = 0.f;
#pragma unroll
      for (int nj = 0; nj < 8; ++nj) {
        float v = acc[mi][nj][r] + b2v[nj];
        v = v > 0.f ? v : 0.f;
        s += v * w3v[nj];
      }
      s += __shfl_xor(s, 1);
      s += __shfl_xor(s, 2);
      s += __shfl_xor(s, 4);
      s += __shfl_xor(s, 8);
      if ((lane & 15) == 0) {
        int m = m0 + wave * 32 + mi * 16 + (lane >> 4) * 4 + r;
        float logit = s + b3p;
        out[(size_t)m * 29 + p] = 1.f / (1.f + __expf(-logit));
      }
    }
  }
}

// ---------------- launch ----------------
extern "C" void kernel_launch(void* const* d_in, const int* in_sizes, int n_in,
                              void* d_out, int out_size, void* d_ws, size_t ws_size,
                              hipStream_t stream) {
  const float* features = (const float*)d_in[0];
  const float* W1 = (const float*)d_in[1];
  const float* b1 = (const float*)d_in[2];
  const float* W2 = (const float*)d_in[3];
  const float* b2 = (const float*)d_in[4];
  const float* W3 = (const float*)d_in[5];
  const float* b3 = (const float*)d_in[6];
  float* out = (float*)d_out;

  char* ws = (char*)d_ws;
  const size_t featB = (size_t)4096 * 8192 * 2;       // 64 MB
  const size_t h1B   = (size_t)29 * 4096 * 256 * 2;   // 58 MB
  const size_t w2B   = (size_t)29 * 128 * 256 * 2;    // 1.9 MB
  const size_t w1pp  = (size_t)256 * 8192 * 2;        // 4 MB per predicate

  unsigned short* featbf = (unsigned short*)ws;
  unsigned short* h1bf   = (unsigned short*)(ws + featB);
  unsigned short* w2t    = (unsigned short*)(ws + featB + h1B);
  unsigned short* w1t    = (unsigned short*)(ws + featB + h1B + w2B);

  size_t base = featB + h1B + w2B;
  size_t rem = (ws_size > base) ? (ws_size - base) : 0;
  int CH = (int)(rem / w1pp);
  if (CH > 29) CH = 29;
  if (CH < 1) CH = 1;

  k_cvt_feat<<<2048, 256, 0, stream>>>(features, featbf);
  k_cvt_w2<<<29, 256, 0, stream>>>(W2, w2t);

  for (int p0 = 0; p0 < 29; p0 += CH) {
    int c = (29 - p0) < CH ? (29 - p0) : CH;
    k_cvt_w1<<<dim3(128, 4, c), 256, 0, stream>>>(W1, w1t, p0);
    k_gemm1<<<dim3(16, c), 512, 0, stream>>>(featbf, w1t, b1, h1bf, p0);
  }

  k_gemm23<<<dim3(32, 29), 256, 0, stream>>>(h1bf, w2t, b2, W3, b3, out);
}